// Round 1
// 173.137 us; speedup vs baseline: 1.0220x; 1.0220x over previous
//
#include <hip/hip_runtime.h>
#include <stdint.h>

// ---------------------------------------------------------------------------
// Bottleneck model: time ~ divergent line-requests x ~4.5cy.
// raster_fast is at its request roofline (4 rec + 1 fzq gathers/pixel, 64 B
// payload is minimal: tc must stay f32 for bit-exact uv frac()).
// This round attacks the producers:
//   - prep_fz: fuses fz reciprocal pass (LDS-staged contiguous reads) with
//     building 8-B packed-fp16 per-vertex tables nrmh/vtxh.
//   - pack_faces2: gathers 8-B aligned dwordx2 records (9 requests/face vs
//     21) and LDS-stages the rec store (1 store request/face vs 4).
//   - raster_fast2: unchanged gather structure; weight load LDS-staged
//     (0.56 -> 0.19 req/pixel). rec layout re-mapped so packed tables copy
//     straight through (bit-identical fp16 values vs previous rec).
// ---------------------------------------------------------------------------

struct H2 { _Float16 x, y; };
static __device__ __forceinline__ uint32_t packh_u(float a, float b) {
    H2 h; h.x = (_Float16)a; h.y = (_Float16)b;
    return __builtin_bit_cast(uint32_t, h);
}
static __device__ __forceinline__ float packh(float a, float b) {
    return __builtin_bit_cast(float, packh_u(a, b));
}
static __device__ __forceinline__ float asf(uint32_t u) {
    return __builtin_bit_cast(float, u);
}
static __device__ __forceinline__ float2 unph(float w) {
    H2 h = __builtin_bit_cast(H2, w);
    return make_float2((float)h.x, (float)h.y);
}

// rec layout (16 floats / 64 B per face):
//  w0..w5  : tc f32  (t0.x t0.y t1.x t1.y t2.x t2.y)
//  w6..w8  : (n0.x,n0.y) (n1.x,n1.y) (n2.x,n2.y)   packed halfs
//  w9      : (n0.z,n1.z)
//  w10     : (n2.z,v0.z)
//  w11..w13: (v0.x,v0.y) (v1.x,v1.y) (v2.x,v2.y)
//  w14     : (v1.z,v2.z)
//  w15     : pad

// prep: build 8-B fp16 vertex tables + fz reciprocals (LDS-staged reads).
__global__ __launch_bounds__(256) void prep_fz(
    const float* __restrict__ nrm, const float* __restrict__ vtx,
    const float* __restrict__ fuvz,
    uint2* __restrict__ nrmh, uint2* __restrict__ vtxh,
    float4* __restrict__ fzq, int V, long BF)
{
    __shared__ float sf[2304];           // 256 faces * 9 floats
    const int tid = threadIdx.x;
    const long base = (long)blockIdx.x * 256;
    const long i = base + tid;

    if (nrmh != nullptr && i < V) {      // per-vertex fp16 tables (8 B, aligned)
        const float* n = nrm + i * 3;
        const float* v = vtx + i * 3;
        nrmh[i] = make_uint2(packh_u(n[0], n[1]), packh_u(n[2], 0.0f));
        vtxh[i] = make_uint2(packh_u(v[0], v[1]), packh_u(v[2], 0.0f));
    }

    if (base + 256 <= BF) {              // full block: contiguous float4 stage
        const float4* src = (const float4*)(fuvz + base * 9);
        float4* d = (float4*)sf;
        d[tid]       = src[tid];
        d[tid + 256] = src[tid + 256];
        if (tid < 64) d[tid + 512] = src[tid + 512];
        __syncthreads();
        fzq[i] = make_float4(__fdiv_rn(1.0f, sf[tid * 9 + 2]),
                             __fdiv_rn(1.0f, sf[tid * 9 + 5]),
                             __fdiv_rn(1.0f, sf[tid * 9 + 8]), 0.0f);
    } else if (i < BF) {                 // ragged tail (generic shapes)
        const float* s = fuvz + i * 9;
        fzq[i] = make_float4(__fdiv_rn(1.0f, s[2]),
                             __fdiv_rn(1.0f, s[5]),
                             __fdiv_rn(1.0f, s[8]), 0.0f);
    }
}

// pack via 8-B aligned gathers; rec store LDS-staged coalesced.
__global__ __launch_bounds__(256) void pack_faces2(
    const float* __restrict__ tc,
    const uint2* __restrict__ nrmh, const uint2* __restrict__ vtxh,
    const int* __restrict__ f_vt, const int* __restrict__ f_vn,
    const int* __restrict__ f_v,
    float4* __restrict__ rec, int F, int V)
{
    __shared__ float4 sw[1024];          // 256 faces * 64 B
    const int tid  = threadIdx.x;
    const int base = blockIdx.x * 256;
    const int f    = base + tid;

    if (f < F) {
        float2 t[3]; uint2 N[3], Vv[3];
#pragma unroll
        for (int k = 0; k < 3; ++k) {
            int ivt = f_vt[f * 3 + k];
            ivt = ivt < 0 ? 0 : (ivt >= V ? V - 1 : ivt);
            t[k] = ((const float2*)tc)[ivt];
            int ivn = f_vn[f * 3 + k];
            ivn = ivn < 0 ? 0 : (ivn >= V ? V - 1 : ivn);
            N[k] = nrmh[ivn];
            int iv = f_v[f * 3 + k];
            iv = iv < 0 ? 0 : (iv >= V ? V - 1 : iv);
            Vv[k] = vtxh[iv];
        }
        uint32_t w9  = (N[0].y  & 0xffffu) | (N[1].y  << 16);
        uint32_t w10 = (N[2].y  & 0xffffu) | (Vv[0].y << 16);
        uint32_t w14 = (Vv[1].y & 0xffffu) | (Vv[2].y << 16);
        float4* o = sw + tid * 4;
        o[0] = make_float4(t[0].x, t[0].y, t[1].x, t[1].y);
        o[1] = make_float4(t[2].x, t[2].y, asf(N[0].x), asf(N[1].x));
        o[2] = make_float4(asf(N[2].x), asf(w9), asf(w10), asf(Vv[0].x));
        o[3] = make_float4(asf(Vv[1].x), asf(Vv[2].x), asf(w14), 0.0f);
    }
    __syncthreads();
    const int valid  = F - base;
    const int valid4 = (valid < 256 ? valid : 256) * 4;
    float4* og = rec + (long)base * 4;
#pragma unroll
    for (int j = 0; j < 4; ++j) {
        int k = tid + 256 * j;
        if (k < valid4) og[k] = sw[k];
    }
}

// middle-tier fallback producer (f32 gathers, new rec layout, no tables).
__global__ __launch_bounds__(256) void pack_faces_old(
    const float* __restrict__ tc, const float* __restrict__ nrm,
    const float* __restrict__ vtx,
    const int* __restrict__ f_vt, const int* __restrict__ f_vn,
    const int* __restrict__ f_v,
    float* __restrict__ rec, int F, int V)
{
    int f = blockIdx.x * 256 + threadIdx.x;
    if (f >= F) return;
    float t[6], n[9], v[9];
#pragma unroll
    for (int k = 0; k < 3; ++k) {
        int ivt = f_vt[f * 3 + k];
        ivt = ivt < 0 ? 0 : (ivt >= V ? V - 1 : ivt);
        t[k * 2 + 0] = tc[(long)ivt * 2 + 0];
        t[k * 2 + 1] = tc[(long)ivt * 2 + 1];
        int ivn = f_vn[f * 3 + k];
        ivn = ivn < 0 ? 0 : (ivn >= V ? V - 1 : ivn);
        n[k * 3 + 0] = nrm[(long)ivn * 3 + 0];
        n[k * 3 + 1] = nrm[(long)ivn * 3 + 1];
        n[k * 3 + 2] = nrm[(long)ivn * 3 + 2];
        int iv = f_v[f * 3 + k];
        iv = iv < 0 ? 0 : (iv >= V ? V - 1 : iv);
        v[k * 3 + 0] = vtx[(long)iv * 3 + 0];
        v[k * 3 + 1] = vtx[(long)iv * 3 + 1];
        v[k * 3 + 2] = vtx[(long)iv * 3 + 2];
    }
    float4* o = (float4*)(rec + (long)f * 16);
    o[0] = make_float4(t[0], t[1], t[2], t[3]);
    o[1] = make_float4(t[4], t[5], packh(n[0], n[1]), packh(n[3], n[4]));
    o[2] = make_float4(packh(n[6], n[7]), packh(n[2], n[5]),
                       packh(n[8], v[2]), packh(v[0], v[1]));
    o[3] = make_float4(packh(v[3], v[4]), packh(v[6], v[7]),
                       packh(v[5], v[8]), 0.0f);
}

// Requires HW % 256 == 0 (enforced in launcher).
__global__ __launch_bounds__(256) void raster_fast2(
    const float4* __restrict__ rec,    // F*4 float4 (64 B/face)
    const float4* __restrict__ fzq,    // B*F float4 (reciprocal fz)
    const float* __restrict__ pose,    // B*16
    const float* __restrict__ depth,   // B*HW
    const int*   __restrict__ fim,     // B*HW
    const float* __restrict__ weight,  // B*HW*3
    float* __restrict__ out,           // B*HW*14
    int F, int HW)
{
    __shared__ float sb[256 * 14];
    const int tid = threadIdx.x;
    const int hw  = blockIdx.x * 256 + tid;
    const int b   = blockIdx.y;
    const long p  = (long)b * HW + hw;

    // stage this block's 768 weight floats coalesced (reuse sb)
    {
        const float4* wsrc =
            (const float4*)(weight + ((long)b * HW + (long)blockIdx.x * 256) * 3);
        if (tid < 192) ((float4*)sb)[tid] = wsrc[tid];
    }

    const float* pb = pose + b * 16;
    float R00 = pb[0],  R01 = pb[1],  R02 = pb[2],  t0 = pb[3];
    float R10 = pb[4],  R11 = pb[5],  R12 = pb[6],  t1 = pb[7];
    float R20 = pb[8],  R21 = pb[9],  R22 = pb[10], t2 = pb[11];

    int f = fim[p];
    f = f < 0 ? 0 : (f >= F ? F - 1 : f);
    const float d = depth[p];

    // 5 divergent dwordx4 gathers total (4 rec + 1 fzq):
    const float4* R4 = rec + (long)f * 4;
    float4 a0 = R4[0], a1 = R4[1], a2 = R4[2], a3 = R4[3];
    float4 fz = fzq[(long)b * F + f];

    __syncthreads();
    float w0 = sb[tid * 3 + 0];
    float w1 = sb[tid * 3 + 1];
    float w2 = sb[tid * 3 + 2];
    __syncthreads();     // done reading staged weights before sb is reused

    // wm[k] = ((1/fz)*w)*d — exact np f32 op order (uv wrap sensitivity)
    float wm0 = __fmul_rn(__fmul_rn(fz.x, w0), d);
    float wm1 = __fmul_rn(__fmul_rn(fz.y, w1), d);
    float wm2 = __fmul_rn(__fmul_rn(fz.z, w2), d);

    // uv: bit-exact vs numpy ((a0+a1)+a2), no FMA contraction
    float uv0 = __fadd_rn(__fadd_rn(__fmul_rn(a0.x, wm0), __fmul_rn(a0.z, wm1)),
                          __fmul_rn(a1.x, wm2));
    float uv1 = __fadd_rn(__fadd_rn(__fmul_rn(a0.y, wm0), __fmul_rn(a0.w, wm1)),
                          __fmul_rn(a1.y, wm2));
    uv0 -= floorf(uv0);
    uv1 -= floorf(uv1);

    // unpack per new rec layout
    float2 u6  = unph(a1.z);   // n0.xy
    float2 u7  = unph(a1.w);   // n1.xy
    float2 u8  = unph(a2.x);   // n2.xy
    float2 u9  = unph(a2.y);   // (n0.z, n1.z)
    float2 u10 = unph(a2.z);   // (n2.z, v0.z)
    float2 u11 = unph(a2.w);   // v0.xy
    float2 u12 = unph(a3.x);   // v1.xy
    float2 u13 = unph(a3.y);   // v2.xy
    float2 u14 = unph(a3.z);   // (v1.z, v2.z)

    float n0 = u6.x * wm0 + u7.x * wm1 + u8.x * wm2;
    float n1 = u6.y * wm0 + u7.y * wm1 + u8.y * wm2;
    float n2 = u9.x * wm0 + u9.y * wm1 + u10.x * wm2;

    float p0 = u11.x * wm0 + u12.x * wm1 + u13.x * wm2;
    float p1 = u11.y * wm0 + u12.y * wm1 + u13.y * wm2;
    float p2 = u10.y * wm0 + u14.x * wm1 + u14.y * wm2;

    float nn = sqrtf(n0 * n0 + n1 * n1 + n2 * n2);
    float ni = 1.0f / fmaxf(nn, 1e-12f);
    float m0 = n0 * ni, m1 = n1 * ni, m2 = n2 * ni;

    float c0 = R00 * m0 + R01 * m1 + R02 * m2;
    float c1 = R10 * m0 + R11 * m1 + R12 * m2;
    float c2 = R20 * m0 + R21 * m1 + R22 * m2;
    float cn = sqrtf(c0 * c0 + c1 * c1 + c2 * c2);
    float ci = 1.0f / fmaxf(cn, 1e-12f);
    c0 *= ci; c1 *= ci; c2 *= ci;

    float q0 = R00 * p0 + R01 * p1 + R02 * p2 + t0;
    float q1 = R10 * p0 + R11 * p1 + R12 * p2 + t1;
    float q2 = R20 * p0 + R21 * p1 + R22 * p2 + t2;

    // stage 14 channels in LDS, then stream 14336 B coalesced
    float* s = sb + tid * 14;
    s[0]  = uv0; s[1]  = uv1;
    s[2]  = m0;  s[3]  = m1;  s[4]  = m2;
    s[5]  = c0;  s[6]  = c1;  s[7]  = c2;
    s[8]  = p0;  s[9]  = p1;  s[10] = p2;
    s[11] = q0;  s[12] = q1;  s[13] = q2;
    __syncthreads();

    float4* og = (float4*)(out + ((long)b * HW + (long)blockIdx.x * 256) * 14);
    const float4* sv = (const float4*)sb;
#pragma unroll
    for (int j = 0; j < 4; ++j) {
        int k = tid + 256 * j;
        if (k < 896) og[k] = sv[k];
    }
}

// ---- final fallback: the proven round-2 single-kernel path ----------------
__global__ __launch_bounds__(256) void raster_kernel(
    const float* __restrict__ vertices, const float* __restrict__ texcoords,
    const float* __restrict__ normals,
    const int* __restrict__ f_vt, const int* __restrict__ f_vn,
    const int* __restrict__ f_v,
    const float* __restrict__ pose, const float* __restrict__ depth,
    const int* __restrict__ fim, const float* __restrict__ weight,
    const float* __restrict__ fuvz, float* __restrict__ out, int F, int V,
    int HW)
{
    const int hw = blockIdx.x * 256 + threadIdx.x;
    if (hw >= HW) return;
    const int b  = blockIdx.y;
    const int p  = b * HW + hw;
    const float* pb = pose + b * 16;
    float R00 = pb[0], R01 = pb[1], R02 = pb[2],  t0 = pb[3];
    float R10 = pb[4], R11 = pb[5], R12 = pb[6],  t1 = pb[7];
    float R20 = pb[8], R21 = pb[9], R22 = pb[10], t2 = pb[11];
    int f = fim[p];
    f = f < 0 ? 0 : (f >= F ? F - 1 : f);
    const float d = depth[p];
    const float* fz = fuvz + ((long)b * F + f) * 9;
    float wm[3];
#pragma unroll
    for (int k = 0; k < 3; ++k)
        wm[k] = __fmul_rn(__fmul_rn(__fdiv_rn(1.0f, fz[k * 3 + 2]),
                                    weight[(long)p * 3 + k]), d);
    float u0t[3], u1t[3];
    float n0 = 0.f, n1 = 0.f, n2 = 0.f, p0 = 0.f, p1 = 0.f, p2 = 0.f;
#pragma unroll
    for (int k = 0; k < 3; ++k) {
        int ivt = f_vt[f * 3 + k], ivn = f_vn[f * 3 + k], iv = f_v[f * 3 + k];
        ivt = ivt < 0 ? 0 : (ivt >= V ? V - 1 : ivt);
        ivn = ivn < 0 ? 0 : (ivn >= V ? V - 1 : ivn);
        iv  = iv  < 0 ? 0 : (iv  >= V ? V - 1 : iv);
        const float* tc = texcoords + (long)ivt * 2;
        u0t[k] = __fmul_rn(tc[0], wm[k]);
        u1t[k] = __fmul_rn(tc[1], wm[k]);
        const float* nr = normals + (long)ivn * 3;
        n0 += nr[0] * wm[k]; n1 += nr[1] * wm[k]; n2 += nr[2] * wm[k];
        const float* vv = vertices + (long)iv * 3;
        p0 += vv[0] * wm[k]; p1 += vv[1] * wm[k]; p2 += vv[2] * wm[k];
    }
    float uv0 = __fadd_rn(__fadd_rn(u0t[0], u0t[1]), u0t[2]);
    float uv1 = __fadd_rn(__fadd_rn(u1t[0], u1t[1]), u1t[2]);
    uv0 -= floorf(uv0); uv1 -= floorf(uv1);
    float nn = sqrtf(n0 * n0 + n1 * n1 + n2 * n2);
    float ni = 1.0f / fmaxf(nn, 1e-12f);
    float m0 = n0 * ni, m1 = n1 * ni, m2 = n2 * ni;
    float c0 = R00 * m0 + R01 * m1 + R02 * m2;
    float c1 = R10 * m0 + R11 * m1 + R12 * m2;
    float c2 = R20 * m0 + R21 * m1 + R22 * m2;
    float cn = sqrtf(c0 * c0 + c1 * c1 + c2 * c2);
    float ci = 1.0f / fmaxf(cn, 1e-12f);
    c0 *= ci; c1 *= ci; c2 *= ci;
    float q0 = R00 * p0 + R01 * p1 + R02 * p2 + t0;
    float q1 = R10 * p0 + R11 * p1 + R12 * p2 + t1;
    float q2 = R20 * p0 + R21 * p1 + R22 * p2 + t2;
    float2* o = (float2*)(out + (long)p * 14);
    o[0] = make_float2(uv0, uv1); o[1] = make_float2(m0, m1);
    o[2] = make_float2(m2, c0);   o[3] = make_float2(c1, c2);
    o[4] = make_float2(p0, p1);   o[5] = make_float2(p2, q0);
    o[6] = make_float2(q1, q2);
}

extern "C" void kernel_launch(void* const* d_in, const int* in_sizes, int n_in,
                              void* d_out, int out_size, void* d_ws, size_t ws_size,
                              hipStream_t stream) {
    const float* vertices  = (const float*)d_in[0];
    const float* texcoords = (const float*)d_in[1];
    const float* normals   = (const float*)d_in[2];
    const int*   f_vt      = (const int*)  d_in[3];
    const int*   f_vn      = (const int*)  d_in[4];
    const int*   f_v       = (const int*)  d_in[5];
    const float* pose      = (const float*)d_in[6];
    const float* depth     = (const float*)d_in[7];
    const int*   fim       = (const int*)  d_in[8];
    const float* weight    = (const float*)d_in[9];
    const float* fuvz      = (const float*)d_in[11];   // d_in[10] v_uvz: dead
    float* out = (float*)d_out;

    const int B  = in_sizes[6] / 16;
    const int F  = in_sizes[3] / 3;
    const int V  = in_sizes[1] / 2;
    const int HW = in_sizes[7] / B;
    const long BF = (long)B * F;

    const size_t rec_bytes = (size_t)F * 64;            // 12.8 MB
    const size_t fzq_bytes = (size_t)BF * 16;           // 12.8 MB
    const size_t tab_bytes = (size_t)V * 8;             // 0.8 MB each
    const bool base_ok = d_ws != nullptr &&
                         (((uintptr_t)d_ws) & 15) == 0 &&
                         (HW % 256) == 0;
    const bool ws_new = base_ok &&
                        ws_size >= rec_bytes + fzq_bytes + 2 * tab_bytes;
    const bool ws_old = base_ok && ws_size >= rec_bytes + fzq_bytes;

    if (ws_new) {
        float* rec  = (float*)d_ws;
        float* fzq  = (float*)((char*)d_ws + rec_bytes);
        uint2* nrmh = (uint2*)((char*)d_ws + rec_bytes + fzq_bytes);
        uint2* vtxh = (uint2*)((char*)d_ws + rec_bytes + fzq_bytes + tab_bytes);
        long nb = BF > (long)V ? BF : (long)V;
        prep_fz<<<(unsigned)((nb + 255) / 256), 256, 0, stream>>>(
            normals, vertices, fuvz, nrmh, vtxh, (float4*)fzq, V, BF);
        pack_faces2<<<(F + 255) / 256, 256, 0, stream>>>(
            texcoords, nrmh, vtxh, f_vt, f_vn, f_v, (float4*)rec, F, V);
        dim3 grid(HW / 256, B);
        raster_fast2<<<grid, 256, 0, stream>>>(
            (const float4*)rec, (const float4*)fzq, pose, depth, fim, weight,
            out, F, HW);
    } else if (ws_old) {
        float* rec = (float*)d_ws;
        float* fzq = (float*)((char*)d_ws + rec_bytes);
        prep_fz<<<(unsigned)((BF + 255) / 256), 256, 0, stream>>>(
            normals, vertices, fuvz, nullptr, nullptr, (float4*)fzq, V, BF);
        pack_faces_old<<<(F + 255) / 256, 256, 0, stream>>>(
            texcoords, normals, vertices, f_vt, f_vn, f_v, rec, F, V);
        dim3 grid(HW / 256, B);
        raster_fast2<<<grid, 256, 0, stream>>>(
            (const float4*)rec, (const float4*)fzq, pose, depth, fim, weight,
            out, F, HW);
    } else {
        dim3 grid((HW + 255) / 256, B);
        raster_kernel<<<grid, 256, 0, stream>>>(
            vertices, texcoords, normals, f_vt, f_vn, f_v,
            pose, depth, fim, weight, fuvz, out, F, V, HW);
    }
}

// Round 2
// 171.568 us; speedup vs baseline: 1.0314x; 1.0091x over previous
//
#include <hip/hip_runtime.h>
#include <stdint.h>

// ---------------------------------------------------------------------------
// Bottleneck model: time ~ divergent line-requests x ~4.5cy, OR L2-miss bound
// (both fit 45us). This round discriminates:
//   - raster_fast3: reverts round-1 weight-LDS staging (proven -2us: the two
//     extra __syncthreads cost more than 0.4 coalesced req/px saved) and adds
//     batch->XCD affinity swizzle (1-D grid, b = (id&7)>>1): each batch's
//     3.2 MB fzq slice becomes L2-resident on its XCD pair instead of all 4
//     batches thrashing every XCD's 4 MB L2 with a 25.6 MB working set.
//   - producers unchanged (round-1 forms, ~2x faster than round 0, out of
//     top-5 by a wide margin).
// If FETCH_SIZE/dur don't move, the TA request-pipe model is confirmed and
// raster is at its structural roofline (5 divergent dwordx4/px minimum).
// ---------------------------------------------------------------------------

struct H2 { _Float16 x, y; };
static __device__ __forceinline__ uint32_t packh_u(float a, float b) {
    H2 h; h.x = (_Float16)a; h.y = (_Float16)b;
    return __builtin_bit_cast(uint32_t, h);
}
static __device__ __forceinline__ float packh(float a, float b) {
    return __builtin_bit_cast(float, packh_u(a, b));
}
static __device__ __forceinline__ float asf(uint32_t u) {
    return __builtin_bit_cast(float, u);
}
static __device__ __forceinline__ float2 unph(float w) {
    H2 h = __builtin_bit_cast(H2, w);
    return make_float2((float)h.x, (float)h.y);
}

// rec layout (16 floats / 64 B per face):
//  w0..w5  : tc f32  (t0.x t0.y t1.x t1.y t2.x t2.y)
//  w6..w8  : (n0.x,n0.y) (n1.x,n1.y) (n2.x,n2.y)   packed halfs
//  w9      : (n0.z,n1.z)
//  w10     : (n2.z,v0.z)
//  w11..w13: (v0.x,v0.y) (v1.x,v1.y) (v2.x,v2.y)
//  w14     : (v1.z,v2.z)
//  w15     : pad

// prep: build 8-B fp16 vertex tables + fz reciprocals (LDS-staged reads).
__global__ __launch_bounds__(256) void prep_fz(
    const float* __restrict__ nrm, const float* __restrict__ vtx,
    const float* __restrict__ fuvz,
    uint2* __restrict__ nrmh, uint2* __restrict__ vtxh,
    float4* __restrict__ fzq, int V, long BF)
{
    __shared__ float sf[2304];           // 256 faces * 9 floats
    const int tid = threadIdx.x;
    const long base = (long)blockIdx.x * 256;
    const long i = base + tid;

    if (nrmh != nullptr && i < V) {      // per-vertex fp16 tables (8 B, aligned)
        const float* n = nrm + i * 3;
        const float* v = vtx + i * 3;
        nrmh[i] = make_uint2(packh_u(n[0], n[1]), packh_u(n[2], 0.0f));
        vtxh[i] = make_uint2(packh_u(v[0], v[1]), packh_u(v[2], 0.0f));
    }

    if (base + 256 <= BF) {              // full block: contiguous float4 stage
        const float4* src = (const float4*)(fuvz + base * 9);
        float4* d = (float4*)sf;
        d[tid]       = src[tid];
        d[tid + 256] = src[tid + 256];
        if (tid < 64) d[tid + 512] = src[tid + 512];
        __syncthreads();
        fzq[i] = make_float4(__fdiv_rn(1.0f, sf[tid * 9 + 2]),
                             __fdiv_rn(1.0f, sf[tid * 9 + 5]),
                             __fdiv_rn(1.0f, sf[tid * 9 + 8]), 0.0f);
    } else if (i < BF) {                 // ragged tail (generic shapes)
        const float* s = fuvz + i * 9;
        fzq[i] = make_float4(__fdiv_rn(1.0f, s[2]),
                             __fdiv_rn(1.0f, s[5]),
                             __fdiv_rn(1.0f, s[8]), 0.0f);
    }
}

// pack via 8-B aligned gathers; rec store LDS-staged coalesced.
__global__ __launch_bounds__(256) void pack_faces2(
    const float* __restrict__ tc,
    const uint2* __restrict__ nrmh, const uint2* __restrict__ vtxh,
    const int* __restrict__ f_vt, const int* __restrict__ f_vn,
    const int* __restrict__ f_v,
    float4* __restrict__ rec, int F, int V)
{
    __shared__ float4 sw[1024];          // 256 faces * 64 B
    const int tid  = threadIdx.x;
    const int base = blockIdx.x * 256;
    const int f    = base + tid;

    if (f < F) {
        float2 t[3]; uint2 N[3], Vv[3];
#pragma unroll
        for (int k = 0; k < 3; ++k) {
            int ivt = f_vt[f * 3 + k];
            ivt = ivt < 0 ? 0 : (ivt >= V ? V - 1 : ivt);
            t[k] = ((const float2*)tc)[ivt];
            int ivn = f_vn[f * 3 + k];
            ivn = ivn < 0 ? 0 : (ivn >= V ? V - 1 : ivn);
            N[k] = nrmh[ivn];
            int iv = f_v[f * 3 + k];
            iv = iv < 0 ? 0 : (iv >= V ? V - 1 : iv);
            Vv[k] = vtxh[iv];
        }
        uint32_t w9  = (N[0].y  & 0xffffu) | (N[1].y  << 16);
        uint32_t w10 = (N[2].y  & 0xffffu) | (Vv[0].y << 16);
        uint32_t w14 = (Vv[1].y & 0xffffu) | (Vv[2].y << 16);
        float4* o = sw + tid * 4;
        o[0] = make_float4(t[0].x, t[0].y, t[1].x, t[1].y);
        o[1] = make_float4(t[2].x, t[2].y, asf(N[0].x), asf(N[1].x));
        o[2] = make_float4(asf(N[2].x), asf(w9), asf(w10), asf(Vv[0].x));
        o[3] = make_float4(asf(Vv[1].x), asf(Vv[2].x), asf(w14), 0.0f);
    }
    __syncthreads();
    const int valid  = F - base;
    const int valid4 = (valid < 256 ? valid : 256) * 4;
    float4* og = rec + (long)base * 4;
#pragma unroll
    for (int j = 0; j < 4; ++j) {
        int k = tid + 256 * j;
        if (k < valid4) og[k] = sw[k];
    }
}

// middle-tier fallback producer (f32 gathers, new rec layout, no tables).
__global__ __launch_bounds__(256) void pack_faces_old(
    const float* __restrict__ tc, const float* __restrict__ nrm,
    const float* __restrict__ vtx,
    const int* __restrict__ f_vt, const int* __restrict__ f_vn,
    const int* __restrict__ f_v,
    float* __restrict__ rec, int F, int V)
{
    int f = blockIdx.x * 256 + threadIdx.x;
    if (f >= F) return;
    float t[6], n[9], v[9];
#pragma unroll
    for (int k = 0; k < 3; ++k) {
        int ivt = f_vt[f * 3 + k];
        ivt = ivt < 0 ? 0 : (ivt >= V ? V - 1 : ivt);
        t[k * 2 + 0] = tc[(long)ivt * 2 + 0];
        t[k * 2 + 1] = tc[(long)ivt * 2 + 1];
        int ivn = f_vn[f * 3 + k];
        ivn = ivn < 0 ? 0 : (ivn >= V ? V - 1 : ivn);
        n[k * 3 + 0] = nrm[(long)ivn * 3 + 0];
        n[k * 3 + 1] = nrm[(long)ivn * 3 + 1];
        n[k * 3 + 2] = nrm[(long)ivn * 3 + 2];
        int iv = f_v[f * 3 + k];
        iv = iv < 0 ? 0 : (iv >= V ? V - 1 : iv);
        v[k * 3 + 0] = vtx[(long)iv * 3 + 0];
        v[k * 3 + 1] = vtx[(long)iv * 3 + 1];
        v[k * 3 + 2] = vtx[(long)iv * 3 + 2];
    }
    float4* o = (float4*)(rec + (long)f * 16);
    o[0] = make_float4(t[0], t[1], t[2], t[3]);
    o[1] = make_float4(t[4], t[5], packh(n[0], n[1]), packh(n[3], n[4]));
    o[2] = make_float4(packh(n[6], n[7]), packh(n[2], n[5]),
                       packh(n[8], v[2]), packh(v[0], v[1]));
    o[3] = make_float4(packh(v[3], v[4]), packh(v[6], v[7]),
                       packh(v[5], v[8]), 0.0f);
}

// 1-D grid; swz=1 => batch->XCD affinity (requires B==4, nx even, grid%8==0).
// Requires HW % 256 == 0 (enforced in launcher).
__global__ __launch_bounds__(256) void raster_fast3(
    const float4* __restrict__ rec,    // F*4 float4 (64 B/face)
    const float4* __restrict__ fzq,    // B*F float4 (reciprocal fz)
    const float* __restrict__ pose,    // B*16
    const float* __restrict__ depth,   // B*HW
    const int*   __restrict__ fim,     // B*HW
    const float* __restrict__ weight,  // B*HW*3
    float* __restrict__ out,           // B*HW*14
    int F, int HW, int nx, int swz)
{
    __shared__ float sb[256 * 14];
    const int tid = threadIdx.x;
    const int id  = blockIdx.x;
    int b, x;
    if (swz) {
        // xcd = id & 7 on MI355X round-robin dispatch; 2 XCDs per batch.
        const int xcd = id & 7;
        b = xcd >> 1;
        x = (id >> 3) + ((xcd & 1) ? (nx >> 1) : 0);
    } else {
        b = id / nx;
        x = id - b * nx;
    }
    const int hw  = x * 256 + tid;
    const long p  = (long)b * HW + hw;

    const float* pb = pose + b * 16;
    float R00 = pb[0],  R01 = pb[1],  R02 = pb[2],  t0 = pb[3];
    float R10 = pb[4],  R11 = pb[5],  R12 = pb[6],  t1 = pb[7];
    float R20 = pb[8],  R21 = pb[9],  R22 = pb[10], t2 = pb[11];

    int f = fim[p];
    f = f < 0 ? 0 : (f >= F ? F - 1 : f);
    const float d = depth[p];
    float w0 = weight[p * 3 + 0];
    float w1 = weight[p * 3 + 1];
    float w2 = weight[p * 3 + 2];

    // 5 divergent dwordx4 gathers total (4 rec + 1 fzq):
    const float4* R4 = rec + (long)f * 4;
    float4 a0 = R4[0], a1 = R4[1], a2 = R4[2], a3 = R4[3];
    float4 fz = fzq[(long)b * F + f];

    // wm[k] = ((1/fz)*w)*d — exact np f32 op order (uv wrap sensitivity);
    // fz.{x,y,z} already hold __fdiv_rn(1,fz) (hoisted, bit-identical)
    float wm0 = __fmul_rn(__fmul_rn(fz.x, w0), d);
    float wm1 = __fmul_rn(__fmul_rn(fz.y, w1), d);
    float wm2 = __fmul_rn(__fmul_rn(fz.z, w2), d);

    // uv: bit-exact vs numpy ((a0+a1)+a2), no FMA contraction
    float uv0 = __fadd_rn(__fadd_rn(__fmul_rn(a0.x, wm0), __fmul_rn(a0.z, wm1)),
                          __fmul_rn(a1.x, wm2));
    float uv1 = __fadd_rn(__fadd_rn(__fmul_rn(a0.y, wm0), __fmul_rn(a0.w, wm1)),
                          __fmul_rn(a1.y, wm2));
    uv0 -= floorf(uv0);
    uv1 -= floorf(uv1);

    // unpack per rec layout
    float2 u6  = unph(a1.z);   // n0.xy
    float2 u7  = unph(a1.w);   // n1.xy
    float2 u8  = unph(a2.x);   // n2.xy
    float2 u9  = unph(a2.y);   // (n0.z, n1.z)
    float2 u10 = unph(a2.z);   // (n2.z, v0.z)
    float2 u11 = unph(a2.w);   // v0.xy
    float2 u12 = unph(a3.x);   // v1.xy
    float2 u13 = unph(a3.y);   // v2.xy
    float2 u14 = unph(a3.z);   // (v1.z, v2.z)

    float n0 = u6.x * wm0 + u7.x * wm1 + u8.x * wm2;
    float n1 = u6.y * wm0 + u7.y * wm1 + u8.y * wm2;
    float n2 = u9.x * wm0 + u9.y * wm1 + u10.x * wm2;

    float p0 = u11.x * wm0 + u12.x * wm1 + u13.x * wm2;
    float p1 = u11.y * wm0 + u12.y * wm1 + u13.y * wm2;
    float p2 = u10.y * wm0 + u14.x * wm1 + u14.y * wm2;

    float nn = sqrtf(n0 * n0 + n1 * n1 + n2 * n2);
    float ni = 1.0f / fmaxf(nn, 1e-12f);
    float m0 = n0 * ni, m1 = n1 * ni, m2 = n2 * ni;

    float c0 = R00 * m0 + R01 * m1 + R02 * m2;
    float c1 = R10 * m0 + R11 * m1 + R12 * m2;
    float c2 = R20 * m0 + R21 * m1 + R22 * m2;
    float cn = sqrtf(c0 * c0 + c1 * c1 + c2 * c2);
    float ci = 1.0f / fmaxf(cn, 1e-12f);
    c0 *= ci; c1 *= ci; c2 *= ci;

    float q0 = R00 * p0 + R01 * p1 + R02 * p2 + t0;
    float q1 = R10 * p0 + R11 * p1 + R12 * p2 + t1;
    float q2 = R20 * p0 + R21 * p1 + R22 * p2 + t2;

    // stage 14 channels in LDS, then stream 14336 B coalesced
    float* s = sb + tid * 14;
    s[0]  = uv0; s[1]  = uv1;
    s[2]  = m0;  s[3]  = m1;  s[4]  = m2;
    s[5]  = c0;  s[6]  = c1;  s[7]  = c2;
    s[8]  = p0;  s[9]  = p1;  s[10] = p2;
    s[11] = q0;  s[12] = q1;  s[13] = q2;
    __syncthreads();

    float4* og = (float4*)(out + ((long)b * HW + (long)x * 256) * 14);
    const float4* sv = (const float4*)sb;
#pragma unroll
    for (int j = 0; j < 4; ++j) {
        int k = tid + 256 * j;
        if (k < 896) og[k] = sv[k];
    }
}

// ---- final fallback: the proven round-2 single-kernel path ----------------
__global__ __launch_bounds__(256) void raster_kernel(
    const float* __restrict__ vertices, const float* __restrict__ texcoords,
    const float* __restrict__ normals,
    const int* __restrict__ f_vt, const int* __restrict__ f_vn,
    const int* __restrict__ f_v,
    const float* __restrict__ pose, const float* __restrict__ depth,
    const int* __restrict__ fim, const float* __restrict__ weight,
    const float* __restrict__ fuvz, float* __restrict__ out, int F, int V,
    int HW)
{
    const int hw = blockIdx.x * 256 + threadIdx.x;
    if (hw >= HW) return;
    const int b  = blockIdx.y;
    const int p  = b * HW + hw;
    const float* pb = pose + b * 16;
    float R00 = pb[0], R01 = pb[1], R02 = pb[2],  t0 = pb[3];
    float R10 = pb[4], R11 = pb[5], R12 = pb[6],  t1 = pb[7];
    float R20 = pb[8], R21 = pb[9], R22 = pb[10], t2 = pb[11];
    int f = fim[p];
    f = f < 0 ? 0 : (f >= F ? F - 1 : f);
    const float d = depth[p];
    const float* fz = fuvz + ((long)b * F + f) * 9;
    float wm[3];
#pragma unroll
    for (int k = 0; k < 3; ++k)
        wm[k] = __fmul_rn(__fmul_rn(__fdiv_rn(1.0f, fz[k * 3 + 2]),
                                    weight[(long)p * 3 + k]), d);
    float u0t[3], u1t[3];
    float n0 = 0.f, n1 = 0.f, n2 = 0.f, p0 = 0.f, p1 = 0.f, p2 = 0.f;
#pragma unroll
    for (int k = 0; k < 3; ++k) {
        int ivt = f_vt[f * 3 + k], ivn = f_vn[f * 3 + k], iv = f_v[f * 3 + k];
        ivt = ivt < 0 ? 0 : (ivt >= V ? V - 1 : ivt);
        ivn = ivn < 0 ? 0 : (ivn >= V ? V - 1 : ivn);
        iv  = iv  < 0 ? 0 : (iv  >= V ? V - 1 : iv);
        const float* tc = texcoords + (long)ivt * 2;
        u0t[k] = __fmul_rn(tc[0], wm[k]);
        u1t[k] = __fmul_rn(tc[1], wm[k]);
        const float* nr = normals + (long)ivn * 3;
        n0 += nr[0] * wm[k]; n1 += nr[1] * wm[k]; n2 += nr[2] * wm[k];
        const float* vv = vertices + (long)iv * 3;
        p0 += vv[0] * wm[k]; p1 += vv[1] * wm[k]; p2 += vv[2] * wm[k];
    }
    float uv0 = __fadd_rn(__fadd_rn(u0t[0], u0t[1]), u0t[2]);
    float uv1 = __fadd_rn(__fadd_rn(u1t[0], u1t[1]), u1t[2]);
    uv0 -= floorf(uv0); uv1 -= floorf(uv1);
    float nn = sqrtf(n0 * n0 + n1 * n1 + n2 * n2);
    float ni = 1.0f / fmaxf(nn, 1e-12f);
    float m0 = n0 * ni, m1 = n1 * ni, m2 = n2 * ni;
    float c0 = R00 * m0 + R01 * m1 + R02 * m2;
    float c1 = R10 * m0 + R11 * m1 + R12 * m2;
    float c2 = R20 * m0 + R21 * m1 + R22 * m2;
    float cn = sqrtf(c0 * c0 + c1 * c1 + c2 * c2);
    float ci = 1.0f / fmaxf(cn, 1e-12f);
    c0 *= ci; c1 *= ci; c2 *= ci;
    float q0 = R00 * p0 + R01 * p1 + R02 * p2 + t0;
    float q1 = R10 * p0 + R11 * p1 + R12 * p2 + t1;
    float q2 = R20 * p0 + R21 * p1 + R22 * p2 + t2;
    float2* o = (float2*)(out + (long)p * 14);
    o[0] = make_float2(uv0, uv1); o[1] = make_float2(m0, m1);
    o[2] = make_float2(m2, c0);   o[3] = make_float2(c1, c2);
    o[4] = make_float2(p0, p1);   o[5] = make_float2(p2, q0);
    o[6] = make_float2(q1, q2);
}

extern "C" void kernel_launch(void* const* d_in, const int* in_sizes, int n_in,
                              void* d_out, int out_size, void* d_ws, size_t ws_size,
                              hipStream_t stream) {
    const float* vertices  = (const float*)d_in[0];
    const float* texcoords = (const float*)d_in[1];
    const float* normals   = (const float*)d_in[2];
    const int*   f_vt      = (const int*)  d_in[3];
    const int*   f_vn      = (const int*)  d_in[4];
    const int*   f_v       = (const int*)  d_in[5];
    const float* pose      = (const float*)d_in[6];
    const float* depth     = (const float*)d_in[7];
    const int*   fim       = (const int*)  d_in[8];
    const float* weight    = (const float*)d_in[9];
    const float* fuvz      = (const float*)d_in[11];   // d_in[10] v_uvz: dead
    float* out = (float*)d_out;

    const int B  = in_sizes[6] / 16;
    const int F  = in_sizes[3] / 3;
    const int V  = in_sizes[1] / 2;
    const int HW = in_sizes[7] / B;
    const long BF = (long)B * F;

    const size_t rec_bytes = (size_t)F * 64;            // 12.8 MB
    const size_t fzq_bytes = (size_t)BF * 16;           // 12.8 MB
    const size_t tab_bytes = (size_t)V * 8;             // 0.8 MB each
    const bool base_ok = d_ws != nullptr &&
                         (((uintptr_t)d_ws) & 15) == 0 &&
                         (HW % 256) == 0;
    const bool ws_new = base_ok &&
                        ws_size >= rec_bytes + fzq_bytes + 2 * tab_bytes;
    const bool ws_old = base_ok && ws_size >= rec_bytes + fzq_bytes;

    const int nx = HW / 256;
    // batch->XCD affinity valid when B==4 and nx even (grid % 8 == 0)
    const int swz = (B == 4 && (nx & 1) == 0) ? 1 : 0;

    if (ws_new) {
        float* rec  = (float*)d_ws;
        float* fzq  = (float*)((char*)d_ws + rec_bytes);
        uint2* nrmh = (uint2*)((char*)d_ws + rec_bytes + fzq_bytes);
        uint2* vtxh = (uint2*)((char*)d_ws + rec_bytes + fzq_bytes + tab_bytes);
        long nb = BF > (long)V ? BF : (long)V;
        prep_fz<<<(unsigned)((nb + 255) / 256), 256, 0, stream>>>(
            normals, vertices, fuvz, nrmh, vtxh, (float4*)fzq, V, BF);
        pack_faces2<<<(F + 255) / 256, 256, 0, stream>>>(
            texcoords, nrmh, vtxh, f_vt, f_vn, f_v, (float4*)rec, F, V);
        raster_fast3<<<B * nx, 256, 0, stream>>>(
            (const float4*)rec, (const float4*)fzq, pose, depth, fim, weight,
            out, F, HW, nx, swz);
    } else if (ws_old) {
        float* rec = (float*)d_ws;
        float* fzq = (float*)((char*)d_ws + rec_bytes);
        prep_fz<<<(unsigned)((BF + 255) / 256), 256, 0, stream>>>(
            normals, vertices, fuvz, nullptr, nullptr, (float4*)fzq, V, BF);
        pack_faces_old<<<(F + 255) / 256, 256, 0, stream>>>(
            texcoords, normals, vertices, f_vt, f_vn, f_v, rec, F, V);
        raster_fast3<<<B * nx, 256, 0, stream>>>(
            (const float4*)rec, (const float4*)fzq, pose, depth, fim, weight,
            out, F, HW, nx, swz);
    } else {
        dim3 grid((HW + 255) / 256, B);
        raster_kernel<<<grid, 256, 0, stream>>>(
            vertices, texcoords, normals, f_vt, f_vn, f_v,
            pose, depth, fim, weight, fuvz, out, F, V, HW);
    }
}